// Round 8
// baseline (327.017 us; speedup 1.0000x reference)
//
#include <hip/hip_runtime.h>
#include <math.h>

#define NUM_LEVELS 5
#define NUM_CLASSES 80
#define TOPK 1000
#define CAND_CAP 4096
#define NBINS 256
#define FLOORV 0.5f
#define BIN_W (0.5f / 256.0f)
#define INV_BIN_W (256.0f / 0.5f)
#define ELEMS_PER_BLOCK 2048  // 256 threads * 8 elems (ONE chunk per thread)

struct LevelParams {
    const float* cls[NUM_LEVELS];
    const float* box[NUM_LEVELS];
    const float* pss[NUM_LEVELS];
    int blk_start[NUM_LEVELS + 1];
};

// Fast sigmoid for selection only (err ~1e-6 << bin width 2e-3).
__device__ __forceinline__ float fsig(float x) {
    return __frcp_rn(1.0f + __expf(-x));
}

// Step-rounded f32 sigmoid, numpy scalar semantics (bit-matches golden; R6/R7 pass).
__device__ __forceinline__ float np_sigmoid_f32(float x) {
    float e32 = (float)exp(-(double)x);
    float d = __fadd_rn(1.0f, e32);
    return __fdiv_rn(1.0f, d);
}

__global__ __launch_bounds__(256) void k_hist(LevelParams P, unsigned* hist, float* blockmax) {
    __shared__ unsigned lh[NBINS];
    __shared__ float lmax[4];
    for (int i = threadIdx.x; i < NBINS; i += 256) lh[i] = 0;
    __syncthreads();

    int lev = 0;
    while ((int)blockIdx.x >= P.blk_start[lev + 1]) ++lev;
    const float* __restrict__ cls = P.cls[lev];
    const float* __restrict__ pss = P.pss[lev];
    const int e = (blockIdx.x - P.blk_start[lev]) * ELEMS_PER_BLOCK + (int)threadIdx.x * 8;

    // 3 independent loads, no dependent chain (8-chunk never crosses a row: 80%8==0)
    float4 c0 = *(const float4*)(cls + e);
    float4 c1 = *(const float4*)(cls + e + 4);
    float pvv = pss[e / NUM_CLASSES];

    float sp = fsig(pvv);
    float cs[8] = {c0.x, c0.y, c0.z, c0.w, c1.x, c1.y, c1.z, c1.w};
    float cm = fmaxf(fmaxf(fmaxf(cs[0], cs[1]), fmaxf(cs[2], cs[3])),
                     fmaxf(fmaxf(cs[4], cs[5]), fmaxf(cs[6], cs[7])));
    float smax = sp * fsig(cm);  // monotone: chunk max score
    if (smax >= FLOORV) {
#pragma unroll
        for (int j = 0; j < 8; ++j) {
            float s = sp * fsig(cs[j]);
            if (s >= FLOORV) {
                int b = (int)((s - FLOORV) * INV_BIN_W);
                if (b > NBINS - 1) b = NBINS - 1;
                atomicAdd(&lh[b], 1u);
            }
        }
    }

    // block max (for compact early-exit)
    float bmax = smax;
#pragma unroll
    for (int o = 32; o > 0; o >>= 1) bmax = fmaxf(bmax, __shfl_xor(bmax, o));
    if ((threadIdx.x & 63) == 0) lmax[threadIdx.x >> 6] = bmax;
    __syncthreads();
    if (threadIdx.x == 0)
        blockmax[blockIdx.x] = fmaxf(fmaxf(lmax[0], lmax[1]), fmaxf(lmax[2], lmax[3]));

    for (int i = threadIdx.x; i < NBINS; i += 256) {
        unsigned v = lh[i];
        if (v) atomicAdd(&hist[lev * NBINS + i], v);
    }
}

__global__ __launch_bounds__(320) void k_cutoff(const unsigned* hist, float* cutL) {
    __shared__ unsigned h[NUM_LEVELS * NBINS];
    for (int i = threadIdx.x; i < NUM_LEVELS * NBINS; i += 320) h[i] = hist[i];
    __syncthreads();
    int lev = threadIdx.x;
    if (lev < NUM_LEVELS) {
        long cum = 0;
        int b = NBINS - 1;
        for (; b >= 0; --b) {
            cum += h[lev * NBINS + b];
            if (cum >= TOPK) break;
        }
        int sel = (b <= 0) ? 0 : (b - 1);  // one margin bin below crossing
        cutL[lev] = FLOORV + (float)sel * BIN_W;
    }
}

__global__ __launch_bounds__(256) void k_compact(LevelParams P, const float* cutL,
                                                 const float* blockmax, int* count, int* cand) {
    int lev = 0;
    while ((int)blockIdx.x >= P.blk_start[lev + 1]) ++lev;
    const float L = cutL[lev];
    if (blockmax[blockIdx.x] < L - 2e-4f) return;  // conservative early-exit

    const float* __restrict__ cls = P.cls[lev];
    const float* __restrict__ pss = P.pss[lev];
    const int e = (blockIdx.x - P.blk_start[lev]) * ELEMS_PER_BLOCK + (int)threadIdx.x * 8;

    float4 c0 = *(const float4*)(cls + e);
    float4 c1 = *(const float4*)(cls + e + 4);
    float pvv = pss[e / NUM_CLASSES];

    const float thr = L - 1e-4f;  // conservative vs fsig error & binning
    float sp = fsig(pvv);
    float cs[8] = {c0.x, c0.y, c0.z, c0.w, c1.x, c1.y, c1.z, c1.w};
    float cm = fmaxf(fmaxf(fmaxf(cs[0], cs[1]), fmaxf(cs[2], cs[3])),
                     fmaxf(fmaxf(cs[4], cs[5]), fmaxf(cs[6], cs[7])));
    if (sp * fsig(cm) >= thr) {
#pragma unroll
        for (int j = 0; j < 8; ++j) {
            float s = sp * fsig(cs[j]);
            if (s >= thr) {
                int pos = atomicAdd(&count[lev], 1);
                if (pos < CAND_CAP) cand[lev * CAND_CAP + pos] = e + j;
            }
        }
    }
}

__global__ __launch_bounds__(1024) void k_final(LevelParams P, const int* cand, const int* count,
                                                const int* wptr, const int* hptr, float* out) {
    // Keys = f32 score via step-rounded numpy chain (bit-matches golden).
    // Bit-equal keys -> ascending flat index (stable top_k tie-break).
    __shared__ int ks[CAND_CAP];
    __shared__ int si[CAND_CAP];
    const int lev = blockIdx.x;
    int n = count[lev];
    if (n > CAND_CAP) n = CAND_CAP;
    const float* __restrict__ cls = P.cls[lev];
    const float* __restrict__ pss = P.pss[lev];
    const float* __restrict__ box = P.box[lev];

    for (int i = threadIdx.x; i < CAND_CAP; i += 1024) {
        if (i < n) {
            int idx = cand[lev * CAND_CAP + i];
            float a32 = np_sigmoid_f32(cls[idx]);
            float b32 = np_sigmoid_f32(pss[idx / NUM_CLASSES]);
            float s = __fmul_rn(a32, b32);
            ks[i] = __float_as_int(s);
            si[i] = idx;
        } else {
            ks[i] = 0;
            si[i] = 0x7fffffff;
        }
    }
    __syncthreads();

    for (int k = 2; k <= CAND_CAP; k <<= 1) {
        for (int j = k >> 1; j > 0; j >>= 1) {
            for (int t = threadIdx.x; t < CAND_CAP / 2; t += 1024) {
                int i = ((t & ~(j - 1)) << 1) | (t & (j - 1));
                int ix = i | j;
                int k1 = ks[i], k2 = ks[ix];
                int i1 = si[i], i2 = si[ix];
                bool before = (k1 > k2) || (k1 == k2 && i1 < i2);
                bool dirDesc = ((i & k) == 0);
                if (before != dirDesc) {
                    ks[i] = k2; ks[ix] = k1;
                    si[i] = i2; si[ix] = i1;
                }
            }
            __syncthreads();
        }
    }

    const float w = (float)wptr[0], h = (float)hptr[0];
    const float invw = 1.0f / w, invh = 1.0f / h;
    for (int r = threadIdx.x; r < TOPK; r += 1024) {
        float s = __int_as_float(ks[r]);
        int idx = si[r];
        bool keep = (r < n) && (s > 0.05f);
        int row = lev * TOPK + r;
        float b0 = 0.f, b1 = 0.f, b2 = 0.f, b3 = 0.f;
        if (keep) {
            int a = idx / NUM_CLASSES;
            b0 = fminf(fmaxf(box[a * 4 + 0] * invw, 0.f), 1.f);
            b1 = fminf(fmaxf(box[a * 4 + 1] * invh, 0.f), 1.f);
            b2 = fminf(fmaxf(box[a * 4 + 2] * invw, 0.f), 1.f);
            b3 = fminf(fmaxf(box[a * 4 + 3] * invh, 0.f), 1.f);
        }
        out[row * 4 + 0] = b0;
        out[row * 4 + 1] = b1;
        out[row * 4 + 2] = b2;
        out[row * 4 + 3] = b3;
        out[NUM_LEVELS * TOPK * 4 + row] = keep ? s : 0.0f;
        out[NUM_LEVELS * TOPK * 5 + row] = keep ? (float)(idx % NUM_CLASSES) : -1.0f;
    }
}

extern "C" void kernel_launch(void* const* d_in, const int* in_sizes, int n_in,
                              void* d_out, int out_size, void* d_ws, size_t ws_size,
                              hipStream_t stream) {
    static const int HWS[NUM_LEVELS] = {262144, 65536, 16384, 4096, 1024};

    LevelParams P;
    int blk = 0;
    for (int i = 0; i < NUM_LEVELS; ++i) {
        P.cls[i] = (const float*)d_in[3 * i + 0];
        P.box[i] = (const float*)d_in[3 * i + 1];
        P.pss[i] = (const float*)d_in[3 * i + 2];
        P.blk_start[i] = blk;
        blk += HWS[i] * NUM_CLASSES / ELEMS_PER_BLOCK;  // 10240+2560+640+160+40
    }
    P.blk_start[NUM_LEVELS] = blk;  // 13640

    const int* wp = (const int*)d_in[15];
    const int* hp = (const int*)d_in[16];

    unsigned char* ws = (unsigned char*)d_ws;
    unsigned* hist = (unsigned*)ws;                      // [0, 5120)
    float* cutL = (float*)(ws + 5120);                   // [5120, 5140)
    int* count = (int*)(ws + 5140);                      // [5140, 5160)
    float* blockmax = (float*)(ws + 5184);               // [5184, 59744) 13640*4
    int* cand = (int*)(ws + 59744);                      // [59744, 141664)

    hipMemsetAsync(ws, 0, 5184, stream);
    k_hist<<<blk, 256, 0, stream>>>(P, hist, blockmax);
    k_cutoff<<<1, 320, 0, stream>>>(hist, cutL);
    k_compact<<<blk, 256, 0, stream>>>(P, cutL, blockmax, count, cand);
    k_final<<<NUM_LEVELS, 1024, 0, stream>>>(P, cand, count, wp, hp, (float*)d_out);
}

// Round 9
// 102.622 us; speedup vs baseline: 3.1866x; 3.1866x over previous
//
#include <hip/hip_runtime.h>
#include <math.h>

#define NUM_LEVELS 5
#define NUM_CLASSES 80
#define TOPK 1000
#define CAND_CAP 4096
#define NBINS 256
#define NREP 32
#define FLOORV 0.5f
#define BIN_W (0.5f / 256.0f)
#define INV_BIN_W (256.0f / 0.5f)
#define GROUP_ELEMS 2048      // 256 threads * 8
#define NGROUPS_TOTAL 13640

struct LevelParams {
    const float* cls[NUM_LEVELS];
    const float* box[NUM_LEVELS];
    const float* pss[NUM_LEVELS];
};

// Fast sigmoid for selection only (err ~1e-6 << bin width ~2e-3).
__device__ __forceinline__ float fsig(float x) {
    return __frcp_rn(1.0f + __expf(-x));
}

// Step-rounded f32 sigmoid, numpy scalar semantics (bit-matches golden; R6-R8 pass).
__device__ __forceinline__ float np_sigmoid_f32(float x) {
    float e32 = (float)exp(-(double)x);
    float d = __fadd_rn(1.0f, e32);
    return __fdiv_rn(1.0f, d);
}

// group-id tables (compile-time): gstart {0,10240,12800,13440,13600,13640}

__global__ __launch_bounds__(256) void k_hist(LevelParams P, unsigned* histR, float* gmaxW) {
    __shared__ unsigned lh[NBINS];
    for (int i = threadIdx.x; i < NBINS; i += 256) lh[i] = 0;
    __syncthreads();

    const int bid = blockIdx.x;
    int lev, lb, nb, G, gs;
    if (bid < 1920)      { lev = 0; lb = bid;        nb = 1920; G = 10240; gs = 0; }
    else if (bid < 2400) { lev = 1; lb = bid - 1920; nb = 480;  G = 2560;  gs = 10240; }
    else if (bid < 2520) { lev = 2; lb = bid - 2400; nb = 120;  G = 640;   gs = 12800; }
    else if (bid < 2550) { lev = 3; lb = bid - 2520; nb = 30;   G = 160;   gs = 13440; }
    else                 { lev = 4; lb = bid - 2550; nb = 10;   G = 40;    gs = 13600; }

    const float* __restrict__ cls = P.cls[lev];
    const float* __restrict__ pss = P.pss[lev];
    const int t8 = (int)threadIdx.x * 8;

    int g = lb;
    int e = g * GROUP_ELEMS + t8;
    float4 c0 = *(const float4*)(cls + e);
    float4 c1 = *(const float4*)(cls + e + 4);
    float pv = pss[e / NUM_CLASSES];

    while (g < G) {
        // ---- prefetch next group (2-deep pipeline) ----
        int gn = g + nb;
        int en = ((gn < G) ? gn : g) * GROUP_ELEMS + t8;
        float4 n0 = *(const float4*)(cls + en);
        float4 n1 = *(const float4*)(cls + en + 4);
        float npv = pss[en / NUM_CLASSES];

        // ---- compute current group ----
        float sp = fsig(pv);
        float cs[8] = {c0.x, c0.y, c0.z, c0.w, c1.x, c1.y, c1.z, c1.w};
        float cm = fmaxf(fmaxf(fmaxf(cs[0], cs[1]), fmaxf(cs[2], cs[3])),
                         fmaxf(fmaxf(cs[4], cs[5]), fmaxf(cs[6], cs[7])));
        float smax = sp * fsig(cm);
        if (smax >= FLOORV) {
#pragma unroll
            for (int j = 0; j < 8; ++j) {
                float s = sp * fsig(cs[j]);
                if (s >= FLOORV) {
                    int b = (int)((s - FLOORV) * INV_BIN_W);
                    if (b > NBINS - 1) b = NBINS - 1;
                    atomicAdd(&lh[b], 1u);
                }
            }
        }
        // per-wave group max, plain store (no atomics, no barriers)
        float wm = smax;
#pragma unroll
        for (int o = 32; o > 0; o >>= 1) wm = fmaxf(wm, __shfl_xor(wm, o));
        if ((threadIdx.x & 63) == 0)
            gmaxW[(gs + g) * 4 + (threadIdx.x >> 6)] = wm;

        g = gn; e = en; c0 = n0; c1 = n1; pv = npv;
    }

    __syncthreads();
    // one flush per block into replica (blockIdx & 31): ~16 hits/address total
    unsigned* h = histR + (size_t)(bid & (NREP - 1)) * (NUM_LEVELS * NBINS) + lev * NBINS;
    for (int i = threadIdx.x; i < NBINS; i += 256) {
        unsigned v = lh[i];
        if (v) atomicAdd(&h[i], v);
    }
}

__global__ __launch_bounds__(256) void k_cutoff(const unsigned* histR, float* cutL) {
    __shared__ unsigned sh[NBINS];
    const int lev = blockIdx.x;
    unsigned s = 0;
#pragma unroll
    for (int r = 0; r < NREP; ++r)
        s += histR[(size_t)r * (NUM_LEVELS * NBINS) + lev * NBINS + threadIdx.x];
    sh[threadIdx.x] = s;
    __syncthreads();
    if (threadIdx.x == 0) {
        long cum = 0;
        int b = NBINS - 1;
        for (; b >= 0; --b) {
            cum += sh[b];
            if (cum >= TOPK) break;
        }
        int sel = (b <= 0) ? 0 : (b - 1);  // one margin bin below crossing
        cutL[lev] = FLOORV + (float)sel * BIN_W;
    }
}

__global__ __launch_bounds__(256) void k_compact(LevelParams P, const float* cutL,
                                                 const float* gmaxW, int* count, int* cand) {
    const int bid = blockIdx.x;
    int lev, gl;
    if (bid < 10240)      { lev = 0; gl = bid; }
    else if (bid < 12800) { lev = 1; gl = bid - 10240; }
    else if (bid < 13440) { lev = 2; gl = bid - 12800; }
    else if (bid < 13600) { lev = 3; gl = bid - 13440; }
    else                  { lev = 4; gl = bid - 13600; }

    const float L = cutL[lev];
    float4 gm4 = *(const float4*)(gmaxW + (size_t)bid * 4);
    float gm = fmaxf(fmaxf(gm4.x, gm4.y), fmaxf(gm4.z, gm4.w));
    if (gm < L - 2e-4f) return;  // conservative group early-exit (uniform)

    __shared__ int lcount;
    __shared__ int lbase;
    __shared__ int lbuf[GROUP_ELEMS];
    if (threadIdx.x == 0) lcount = 0;
    __syncthreads();

    const float* __restrict__ cls = P.cls[lev];
    const float* __restrict__ pss = P.pss[lev];
    const int e = gl * GROUP_ELEMS + (int)threadIdx.x * 8;

    float4 c0 = *(const float4*)(cls + e);
    float4 c1 = *(const float4*)(cls + e + 4);
    float pv = pss[e / NUM_CLASSES];

    const float thr = L - 1e-4f;  // conservative vs fsig error & binning
    float sp = fsig(pv);
    float cs[8] = {c0.x, c0.y, c0.z, c0.w, c1.x, c1.y, c1.z, c1.w};
    float cm = fmaxf(fmaxf(fmaxf(cs[0], cs[1]), fmaxf(cs[2], cs[3])),
                     fmaxf(fmaxf(cs[4], cs[5]), fmaxf(cs[6], cs[7])));
    if (sp * fsig(cm) >= thr) {
#pragma unroll
        for (int j = 0; j < 8; ++j) {
            float s = sp * fsig(cs[j]);
            if (s >= thr) {
                int li = atomicAdd(&lcount, 1);
                if (li < GROUP_ELEMS) lbuf[li] = e + j;
            }
        }
    }
    __syncthreads();
    if (threadIdx.x == 0) lbase = atomicAdd(&count[lev], lcount);  // ONE global atomic/block
    __syncthreads();
    const int m = lcount < GROUP_ELEMS ? lcount : GROUP_ELEMS;
    const int base = lbase;
    for (int i = threadIdx.x; i < m; i += 256) {
        int pos = base + i;
        if (pos < CAND_CAP) cand[lev * CAND_CAP + pos] = lbuf[i];
    }
}

__global__ __launch_bounds__(1024) void k_final(LevelParams P, const int* cand, const int* count,
                                                const int* wptr, const int* hptr, float* out) {
    // Keys = f32 score via step-rounded numpy chain (bit-matches golden).
    // Bit-equal keys -> ascending flat index (stable top_k tie-break).
    __shared__ int ks[CAND_CAP];
    __shared__ int si[CAND_CAP];
    const int lev = blockIdx.x;
    int n = count[lev];
    if (n > CAND_CAP) n = CAND_CAP;
    int size = 1024;
    while (size < n) size <<= 1;  // 1024 / 2048 / 4096

    const float* __restrict__ cls = P.cls[lev];
    const float* __restrict__ pss = P.pss[lev];
    const float* __restrict__ box = P.box[lev];

    for (int i = threadIdx.x; i < size; i += 1024) {
        if (i < n) {
            int idx = cand[lev * CAND_CAP + i];
            float a32 = np_sigmoid_f32(cls[idx]);
            float b32 = np_sigmoid_f32(pss[idx / NUM_CLASSES]);
            float s = __fmul_rn(a32, b32);
            ks[i] = __float_as_int(s);
            si[i] = idx;
        } else {
            ks[i] = 0;
            si[i] = 0x7fffffff;
        }
    }
    __syncthreads();

    for (int k = 2; k <= size; k <<= 1) {
        for (int j = k >> 1; j > 0; j >>= 1) {
            for (int t = threadIdx.x; t < (size >> 1); t += 1024) {
                int i = ((t & ~(j - 1)) << 1) | (t & (j - 1));
                int ix = i | j;
                int k1 = ks[i], k2 = ks[ix];
                int i1 = si[i], i2 = si[ix];
                bool before = (k1 > k2) || (k1 == k2 && i1 < i2);
                bool dirDesc = ((i & k) == 0);
                if (before != dirDesc) {
                    ks[i] = k2; ks[ix] = k1;
                    si[i] = i2; si[ix] = i1;
                }
            }
            __syncthreads();
        }
    }

    const float w = (float)wptr[0], h = (float)hptr[0];
    const float invw = 1.0f / w, invh = 1.0f / h;
    for (int r = threadIdx.x; r < TOPK; r += 1024) {
        float s = __int_as_float(ks[r]);
        int idx = si[r];
        bool keep = (r < n) && (s > 0.05f);
        int row = lev * TOPK + r;
        float b0 = 0.f, b1 = 0.f, b2 = 0.f, b3 = 0.f;
        if (keep) {
            int a = idx / NUM_CLASSES;
            b0 = fminf(fmaxf(box[a * 4 + 0] * invw, 0.f), 1.f);
            b1 = fminf(fmaxf(box[a * 4 + 1] * invh, 0.f), 1.f);
            b2 = fminf(fmaxf(box[a * 4 + 2] * invw, 0.f), 1.f);
            b3 = fminf(fmaxf(box[a * 4 + 3] * invh, 0.f), 1.f);
        }
        out[row * 4 + 0] = b0;
        out[row * 4 + 1] = b1;
        out[row * 4 + 2] = b2;
        out[row * 4 + 3] = b3;
        out[NUM_LEVELS * TOPK * 4 + row] = keep ? s : 0.0f;
        out[NUM_LEVELS * TOPK * 5 + row] = keep ? (float)(idx % NUM_CLASSES) : -1.0f;
    }
}

extern "C" void kernel_launch(void* const* d_in, const int* in_sizes, int n_in,
                              void* d_out, int out_size, void* d_ws, size_t ws_size,
                              hipStream_t stream) {
    LevelParams P;
    for (int i = 0; i < NUM_LEVELS; ++i) {
        P.cls[i] = (const float*)d_in[3 * i + 0];
        P.box[i] = (const float*)d_in[3 * i + 1];
        P.pss[i] = (const float*)d_in[3 * i + 2];
    }
    const int* wp = (const int*)d_in[15];
    const int* hp = (const int*)d_in[16];

    unsigned char* ws = (unsigned char*)d_ws;
    unsigned* histR = (unsigned*)ws;                     // 32*1280*4 = 163840  [0,163840)
    float* cutL = (float*)(ws + 163840);                 // 20B [163840,163860)
    int* count = (int*)(ws + 163860);                    // 20B [163860,163880)
    float* gmaxW = (float*)(ws + 163904);                // 13640*4*4 = 218240 [163904,382144)
    int* cand = (int*)(ws + 382208);                     // 81920 [382208,464128)

    hipMemsetAsync(ws, 0, 163880, stream);               // histR + cutL + count
    k_hist<<<2560, 256, 0, stream>>>(P, histR, gmaxW);
    k_cutoff<<<NUM_LEVELS, 256, 0, stream>>>(histR, cutL);
    k_compact<<<NGROUPS_TOTAL, 256, 0, stream>>>(P, cutL, gmaxW, count, cand);
    k_final<<<NUM_LEVELS, 1024, 0, stream>>>(P, cand, count, wp, hp, (float*)d_out);
}

// Round 10
// 99.581 us; speedup vs baseline: 3.2839x; 1.0305x over previous
//
#include <hip/hip_runtime.h>
#include <math.h>

#define NUM_LEVELS 5
#define NUM_CLASSES 80
#define TOPK 1000
#define CAND_CAP 4096
#define NBINS 256
#define NREP 32
#define FLOORV 0.5f
#define BIN_W (0.5f / 256.0f)
#define INV_BIN_W (256.0f / 0.5f)
#define GROUP_ELEMS 2048      // 256 threads * 8
#define NGROUPS_TOTAL 13640

struct LevelParams {
    const float* cls[NUM_LEVELS];
    const float* box[NUM_LEVELS];
    const float* pss[NUM_LEVELS];
};

// Fast sigmoid for selection only (err ~1e-6 << bin width ~2e-3).
__device__ __forceinline__ float fsig(float x) {
    return __frcp_rn(1.0f + __expf(-x));
}

// Step-rounded f32 sigmoid, numpy scalar semantics (bit-matches golden; R6-R9 pass).
__device__ __forceinline__ float np_sigmoid_f32(float x) {
    float e32 = (float)exp(-(double)x);
    float d = __fadd_rn(1.0f, e32);
    return __fdiv_rn(1.0f, d);
}

// Zero histR (32*1280 u32 = 10240 float4) + count[5]. Replaces the runtime's
// pathologically slow fillBuffer (~48 us for 164 KB on graph replay).
__global__ __launch_bounds__(256) void k_zero(float4* histR4, int* count) {
    int i = blockIdx.x * 256 + threadIdx.x;
    histR4[i] = make_float4(0.f, 0.f, 0.f, 0.f);  // grid exactly covers 10240
    if (i < NUM_LEVELS) count[i] = 0;
}

__global__ __launch_bounds__(256) void k_hist(LevelParams P, unsigned* histR, float* gmaxW) {
    __shared__ unsigned lh[NBINS];
    for (int i = threadIdx.x; i < NBINS; i += 256) lh[i] = 0;
    __syncthreads();

    const int bid = blockIdx.x;
    int lev, lb, nb, G, gs;
    if (bid < 1920)      { lev = 0; lb = bid;        nb = 1920; G = 10240; gs = 0; }
    else if (bid < 2400) { lev = 1; lb = bid - 1920; nb = 480;  G = 2560;  gs = 10240; }
    else if (bid < 2520) { lev = 2; lb = bid - 2400; nb = 120;  G = 640;   gs = 12800; }
    else if (bid < 2550) { lev = 3; lb = bid - 2520; nb = 30;   G = 160;   gs = 13440; }
    else                 { lev = 4; lb = bid - 2550; nb = 10;   G = 40;    gs = 13600; }

    const float* __restrict__ cls = P.cls[lev];
    const float* __restrict__ pss = P.pss[lev];
    const int t8 = (int)threadIdx.x * 8;

    int g = lb;
    int e = g * GROUP_ELEMS + t8;
    float4 c0 = *(const float4*)(cls + e);
    float4 c1 = *(const float4*)(cls + e + 4);
    float pv = pss[e / NUM_CLASSES];

    while (g < G) {
        // ---- prefetch next group (2-deep pipeline) ----
        int gn = g + nb;
        int en = ((gn < G) ? gn : g) * GROUP_ELEMS + t8;
        float4 n0 = *(const float4*)(cls + en);
        float4 n1 = *(const float4*)(cls + en + 4);
        float npv = pss[en / NUM_CLASSES];

        // ---- compute current group ----
        float sp = fsig(pv);
        float cs[8] = {c0.x, c0.y, c0.z, c0.w, c1.x, c1.y, c1.z, c1.w};
        float cm = fmaxf(fmaxf(fmaxf(cs[0], cs[1]), fmaxf(cs[2], cs[3])),
                         fmaxf(fmaxf(cs[4], cs[5]), fmaxf(cs[6], cs[7])));
        float smax = sp * fsig(cm);
        if (smax >= FLOORV) {
#pragma unroll
            for (int j = 0; j < 8; ++j) {
                float s = sp * fsig(cs[j]);
                if (s >= FLOORV) {
                    int b = (int)((s - FLOORV) * INV_BIN_W);
                    if (b > NBINS - 1) b = NBINS - 1;
                    atomicAdd(&lh[b], 1u);
                }
            }
        }
        // per-wave group max, plain store (no atomics, no barriers)
        float wm = smax;
#pragma unroll
        for (int o = 32; o > 0; o >>= 1) wm = fmaxf(wm, __shfl_xor(wm, o));
        if ((threadIdx.x & 63) == 0)
            gmaxW[(gs + g) * 4 + (threadIdx.x >> 6)] = wm;

        g = gn; e = en; c0 = n0; c1 = n1; pv = npv;
    }

    __syncthreads();
    // one flush per block into replica (blockIdx & 31): ~16 hits/address total
    unsigned* h = histR + (size_t)(bid & (NREP - 1)) * (NUM_LEVELS * NBINS) + lev * NBINS;
    for (int i = threadIdx.x; i < NBINS; i += 256) {
        unsigned v = lh[i];
        if (v) atomicAdd(&h[i], v);
    }
}

__global__ __launch_bounds__(256) void k_cutoff(const unsigned* histR, float* cutL) {
    __shared__ unsigned sh[NBINS];
    const int lev = blockIdx.x;
    unsigned s = 0;
#pragma unroll
    for (int r = 0; r < NREP; ++r)
        s += histR[(size_t)r * (NUM_LEVELS * NBINS) + lev * NBINS + threadIdx.x];
    sh[threadIdx.x] = s;
    __syncthreads();
    if (threadIdx.x == 0) {
        long cum = 0;
        int b = NBINS - 1;
        for (; b >= 0; --b) {
            cum += sh[b];
            if (cum >= TOPK) break;
        }
        int sel = (b <= 0) ? 0 : (b - 1);  // one margin bin below crossing
        cutL[lev] = FLOORV + (float)sel * BIN_W;
    }
}

__global__ __launch_bounds__(256) void k_compact(LevelParams P, const float* cutL,
                                                 const float* gmaxW, int* count, int* cand) {
    const int bid = blockIdx.x;
    int lev, gl;
    if (bid < 10240)      { lev = 0; gl = bid; }
    else if (bid < 12800) { lev = 1; gl = bid - 10240; }
    else if (bid < 13440) { lev = 2; gl = bid - 12800; }
    else if (bid < 13600) { lev = 3; gl = bid - 13440; }
    else                  { lev = 4; gl = bid - 13600; }

    const float L = cutL[lev];
    float4 gm4 = *(const float4*)(gmaxW + (size_t)bid * 4);
    float gm = fmaxf(fmaxf(gm4.x, gm4.y), fmaxf(gm4.z, gm4.w));
    if (gm < L - 2e-4f) return;  // conservative group early-exit (uniform)

    __shared__ int lcount;
    __shared__ int lbase;
    __shared__ int lbuf[GROUP_ELEMS];
    if (threadIdx.x == 0) lcount = 0;
    __syncthreads();

    const float* __restrict__ cls = P.cls[lev];
    const float* __restrict__ pss = P.pss[lev];
    const int e = gl * GROUP_ELEMS + (int)threadIdx.x * 8;

    float4 c0 = *(const float4*)(cls + e);
    float4 c1 = *(const float4*)(cls + e + 4);
    float pv = pss[e / NUM_CLASSES];

    const float thr = L - 1e-4f;  // conservative vs fsig error & binning
    float sp = fsig(pv);
    float cs[8] = {c0.x, c0.y, c0.z, c0.w, c1.x, c1.y, c1.z, c1.w};
    float cm = fmaxf(fmaxf(fmaxf(cs[0], cs[1]), fmaxf(cs[2], cs[3])),
                     fmaxf(fmaxf(cs[4], cs[5]), fmaxf(cs[6], cs[7])));
    if (sp * fsig(cm) >= thr) {
#pragma unroll
        for (int j = 0; j < 8; ++j) {
            float s = sp * fsig(cs[j]);
            if (s >= thr) {
                int li = atomicAdd(&lcount, 1);
                if (li < GROUP_ELEMS) lbuf[li] = e + j;
            }
        }
    }
    __syncthreads();
    if (threadIdx.x == 0) lbase = atomicAdd(&count[lev], lcount);  // ONE global atomic/block
    __syncthreads();
    const int m = lcount < GROUP_ELEMS ? lcount : GROUP_ELEMS;
    const int base = lbase;
    for (int i = threadIdx.x; i < m; i += 256) {
        int pos = base + i;
        if (pos < CAND_CAP) cand[lev * CAND_CAP + pos] = lbuf[i];
    }
}

__global__ __launch_bounds__(1024) void k_final(LevelParams P, const int* cand, const int* count,
                                                const int* wptr, const int* hptr, float* out) {
    // Keys = f32 score via step-rounded numpy chain (bit-matches golden).
    // Bit-equal keys -> ascending flat index (stable top_k tie-break).
    __shared__ int ks[CAND_CAP];
    __shared__ int si[CAND_CAP];
    const int lev = blockIdx.x;
    int n = count[lev];
    if (n > CAND_CAP) n = CAND_CAP;
    int size = 1024;
    while (size < n) size <<= 1;  // 1024 / 2048 / 4096

    const float* __restrict__ cls = P.cls[lev];
    const float* __restrict__ pss = P.pss[lev];
    const float* __restrict__ box = P.box[lev];

    for (int i = threadIdx.x; i < size; i += 1024) {
        if (i < n) {
            int idx = cand[lev * CAND_CAP + i];
            float a32 = np_sigmoid_f32(cls[idx]);
            float b32 = np_sigmoid_f32(pss[idx / NUM_CLASSES]);
            float s = __fmul_rn(a32, b32);
            ks[i] = __float_as_int(s);
            si[i] = idx;
        } else {
            ks[i] = 0;
            si[i] = 0x7fffffff;
        }
    }
    __syncthreads();

    for (int k = 2; k <= size; k <<= 1) {
        for (int j = k >> 1; j > 0; j >>= 1) {
            for (int t = threadIdx.x; t < (size >> 1); t += 1024) {
                int i = ((t & ~(j - 1)) << 1) | (t & (j - 1));
                int ix = i | j;
                int k1 = ks[i], k2 = ks[ix];
                int i1 = si[i], i2 = si[ix];
                bool before = (k1 > k2) || (k1 == k2 && i1 < i2);
                bool dirDesc = ((i & k) == 0);
                if (before != dirDesc) {
                    ks[i] = k2; ks[ix] = k1;
                    si[i] = i2; si[ix] = i1;
                }
            }
            __syncthreads();
        }
    }

    const float w = (float)wptr[0], h = (float)hptr[0];
    const float invw = 1.0f / w, invh = 1.0f / h;
    for (int r = threadIdx.x; r < TOPK; r += 1024) {
        float s = __int_as_float(ks[r]);
        int idx = si[r];
        bool keep = (r < n) && (s > 0.05f);
        int row = lev * TOPK + r;
        float b0 = 0.f, b1 = 0.f, b2 = 0.f, b3 = 0.f;
        if (keep) {
            int a = idx / NUM_CLASSES;
            b0 = fminf(fmaxf(box[a * 4 + 0] * invw, 0.f), 1.f);
            b1 = fminf(fmaxf(box[a * 4 + 1] * invh, 0.f), 1.f);
            b2 = fminf(fmaxf(box[a * 4 + 2] * invw, 0.f), 1.f);
            b3 = fminf(fmaxf(box[a * 4 + 3] * invh, 0.f), 1.f);
        }
        out[row * 4 + 0] = b0;
        out[row * 4 + 1] = b1;
        out[row * 4 + 2] = b2;
        out[row * 4 + 3] = b3;
        out[NUM_LEVELS * TOPK * 4 + row] = keep ? s : 0.0f;
        out[NUM_LEVELS * TOPK * 5 + row] = keep ? (float)(idx % NUM_CLASSES) : -1.0f;
    }
}

extern "C" void kernel_launch(void* const* d_in, const int* in_sizes, int n_in,
                              void* d_out, int out_size, void* d_ws, size_t ws_size,
                              hipStream_t stream) {
    LevelParams P;
    for (int i = 0; i < NUM_LEVELS; ++i) {
        P.cls[i] = (const float*)d_in[3 * i + 0];
        P.box[i] = (const float*)d_in[3 * i + 1];
        P.pss[i] = (const float*)d_in[3 * i + 2];
    }
    const int* wp = (const int*)d_in[15];
    const int* hp = (const int*)d_in[16];

    unsigned char* ws = (unsigned char*)d_ws;
    unsigned* histR = (unsigned*)ws;                     // 32*1280*4 = 163840  [0,163840)
    float* cutL = (float*)(ws + 163840);                 // 20B [163840,163860)
    int* count = (int*)(ws + 163860);                    // 20B [163860,163880)
    float* gmaxW = (float*)(ws + 163904);                // 13640*4*4 = 218240 [163904,382144)
    int* cand = (int*)(ws + 382208);                     // 81920 [382208,464128)

    k_zero<<<40, 256, 0, stream>>>((float4*)histR, count);   // 10240 float4 + count[5]
    k_hist<<<2560, 256, 0, stream>>>(P, histR, gmaxW);
    k_cutoff<<<NUM_LEVELS, 256, 0, stream>>>(histR, cutL);
    k_compact<<<NGROUPS_TOTAL, 256, 0, stream>>>(P, cutL, gmaxW, count, cand);
    k_final<<<NUM_LEVELS, 1024, 0, stream>>>(P, cand, count, wp, hp, (float*)d_out);
}

// Round 11
// 98.956 us; speedup vs baseline: 3.3047x; 1.0063x over previous
//
#include <hip/hip_runtime.h>
#include <math.h>

#define NUM_LEVELS 5
#define NUM_CLASSES 80
#define TOPK 1000
#define CAND_CAP 4096
#define NBINS 256
#define NREP 32
#define FLOORV 0.5f
#define BIN_W (0.5f / 256.0f)
#define INV_BIN_W (256.0f / 0.5f)
#define GROUP_ELEMS 2048      // 256 threads * 8
#define NGROUPS_TOTAL 13640

struct LevelParams {
    const float* cls[NUM_LEVELS];
    const float* box[NUM_LEVELS];
    const float* pss[NUM_LEVELS];
};

// Step-rounded f32 sigmoid, numpy scalar semantics (bit-matches golden; R6-R10 pass).
__device__ __forceinline__ float np_sigmoid_f32(float x) {
    float e32 = (float)exp(-(double)x);
    float d = __fadd_rn(1.0f, e32);
    return __fdiv_rn(1.0f, d);
}

// Zero histR (32*1280 u32 = 10240 float4) + count[5].
__global__ __launch_bounds__(256) void k_zero(float4* histR4, int* count) {
    int i = blockIdx.x * 256 + threadIdx.x;
    histR4[i] = make_float4(0.f, 0.f, 0.f, 0.f);  // grid exactly covers 10240
    if (i < NUM_LEVELS) count[i] = 0;
}

// Raw-logit selection: s = sig(c)*sig(p) >= T  <=>  e^-c <= 1/(T*(1+e^-p)) - 1
//                                            <=>  c >= -log(1/(T*A) - 1),  A = 1+e^-p.
// One exp+log per row-chunk instead of 2 trans per element.
__global__ __launch_bounds__(256) void k_hist(LevelParams P, unsigned* histR, float* gmaxW) {
    __shared__ unsigned lh[NBINS];
    for (int i = threadIdx.x; i < NBINS; i += 256) lh[i] = 0;
    __syncthreads();

    const int bid = blockIdx.x;
    int lev, lb, nb, G, gs;
    if (bid < 1920)      { lev = 0; lb = bid;        nb = 1920; G = 10240; gs = 0; }
    else if (bid < 2400) { lev = 1; lb = bid - 1920; nb = 480;  G = 2560;  gs = 10240; }
    else if (bid < 2520) { lev = 2; lb = bid - 2400; nb = 120;  G = 640;   gs = 12800; }
    else if (bid < 2550) { lev = 3; lb = bid - 2520; nb = 30;   G = 160;   gs = 13440; }
    else                 { lev = 4; lb = bid - 2550; nb = 10;   G = 40;    gs = 13600; }

    const float* __restrict__ cls = P.cls[lev];
    const float* __restrict__ pss = P.pss[lev];
    const int t8 = (int)threadIdx.x * 8;

    int g = lb;
    int e = g * GROUP_ELEMS + t8;
    float4 c0 = *(const float4*)(cls + e);
    float4 c1 = *(const float4*)(cls + e + 4);
    float pv = pss[e / NUM_CLASSES];

    while (g < G) {
        // ---- prefetch next group (2-deep pipeline) ----
        int gn = g + nb;
        int en = ((gn < G) ? gn : g) * GROUP_ELEMS + t8;
        float4 n0 = *(const float4*)(cls + en);
        float4 n1 = *(const float4*)(cls + en + 4);
        float npv = pss[en / NUM_CLASSES];

        // ---- compute current group (raw-logit floor test) ----
        float cs[8] = {c0.x, c0.y, c0.z, c0.w, c1.x, c1.y, c1.z, c1.w};
        float cm = fmaxf(fmaxf(fmaxf(cs[0], cs[1]), fmaxf(cs[2], cs[3])),
                         fmaxf(fmaxf(cs[4], cs[5]), fmaxf(cs[6], cs[7])));
        float A = 1.0f + __expf(-pv);
        float g2 = 2.0f * __frcp_rn(A) - 1.0f;   // e^-cm <= g2  <=>  smax >= 0.5
        float wm = 0.0f;                         // chunk smax (0 if sub-floor)
        if (g2 > 0.0f) {
            float cmin = -__logf(g2) - 1e-2f;    // conservative raw margin
            if (cm >= cmin) {
                wm = __frcp_rn((1.0f + __expf(-cm)) * A);
#pragma unroll
                for (int j = 0; j < 8; ++j) {
                    if (cs[j] >= cmin) {
                        float s = __frcp_rn((1.0f + __expf(-cs[j])) * A);
                        int b = (int)((s - FLOORV) * INV_BIN_W);
                        if (b < 0) b = 0;                 // admitted extras -> bin 0
                        if (b > NBINS - 1) b = NBINS - 1;
                        atomicAdd(&lh[b], 1u);
                    }
                }
            }
        }
        // per-wave group max, plain store (no atomics, no barriers)
#pragma unroll
        for (int o = 32; o > 0; o >>= 1) wm = fmaxf(wm, __shfl_xor(wm, o));
        if ((threadIdx.x & 63) == 0)
            gmaxW[(gs + g) * 4 + (threadIdx.x >> 6)] = wm;

        g = gn; e = en; c0 = n0; c1 = n1; pv = npv;
    }

    __syncthreads();
    // one flush per block into replica (blockIdx & 31)
    unsigned* h = histR + (size_t)(bid & (NREP - 1)) * (NUM_LEVELS * NBINS) + lev * NBINS;
    for (int i = threadIdx.x; i < NBINS; i += 256) {
        unsigned v = lh[i];
        if (v) atomicAdd(&h[i], v);
    }
}

__global__ __launch_bounds__(256) void k_cutoff(const unsigned* histR, float* cutL) {
    __shared__ unsigned sh[NBINS];
    const int lev = blockIdx.x;
    unsigned s = 0;
#pragma unroll
    for (int r = 0; r < NREP; ++r)
        s += histR[(size_t)r * (NUM_LEVELS * NBINS) + lev * NBINS + threadIdx.x];
    sh[threadIdx.x] = s;
    __syncthreads();
    if (threadIdx.x == 0) {
        long cum = 0;
        int b = NBINS - 1;
        for (; b >= 0; --b) {
            cum += sh[b];
            if (cum >= TOPK) break;
        }
        int sel = (b <= 0) ? 0 : (b - 1);  // one margin bin below crossing
        cutL[lev] = FLOORV + (float)sel * BIN_W;
    }
}

__global__ __launch_bounds__(256) void k_compact(LevelParams P, const float* cutL,
                                                 const float* gmaxW, int* count, int* cand) {
    const int bid = blockIdx.x;
    int lev, gl;
    if (bid < 10240)      { lev = 0; gl = bid; }
    else if (bid < 12800) { lev = 1; gl = bid - 10240; }
    else if (bid < 13440) { lev = 2; gl = bid - 12800; }
    else if (bid < 13600) { lev = 3; gl = bid - 13440; }
    else                  { lev = 4; gl = bid - 13600; }

    const float L = cutL[lev];
    float4 gm4 = *(const float4*)(gmaxW + (size_t)bid * 4);
    float gm = fmaxf(fmaxf(gm4.x, gm4.y), fmaxf(gm4.z, gm4.w));
    if (gm < L - 2e-4f) return;  // conservative group early-exit (uniform)

    __shared__ int lcount;
    __shared__ int lbase;
    __shared__ int lbuf[GROUP_ELEMS];
    if (threadIdx.x == 0) lcount = 0;
    __syncthreads();

    const float* __restrict__ cls = P.cls[lev];
    const float* __restrict__ pss = P.pss[lev];
    const int e = gl * GROUP_ELEMS + (int)threadIdx.x * 8;

    float4 c0 = *(const float4*)(cls + e);
    float4 c1 = *(const float4*)(cls + e + 4);
    float pv = pss[e / NUM_CLASSES];

    const float thr = L - 1e-4f;
    float cs[8] = {c0.x, c0.y, c0.z, c0.w, c1.x, c1.y, c1.z, c1.w};
    float cm = fmaxf(fmaxf(fmaxf(cs[0], cs[1]), fmaxf(cs[2], cs[3])),
                     fmaxf(fmaxf(cs[4], cs[5]), fmaxf(cs[6], cs[7])));
    float A = 1.0f + __expf(-pv);
    float gg = __frcp_rn(thr * A) - 1.0f;     // e^-c <= gg  <=>  s >= thr
    if (gg > 0.0f) {
        float cthr = -__logf(gg) - 1e-2f;     // conservative raw margin
        if (cm >= cthr) {
#pragma unroll
            for (int j = 0; j < 8; ++j) {
                if (cs[j] >= cthr) {
                    int li = atomicAdd(&lcount, 1);
                    if (li < GROUP_ELEMS) lbuf[li] = e + j;
                }
            }
        }
    }
    __syncthreads();
    if (threadIdx.x == 0) lbase = atomicAdd(&count[lev], lcount);  // ONE global atomic/block
    __syncthreads();
    const int m = lcount < GROUP_ELEMS ? lcount : GROUP_ELEMS;
    const int base = lbase;
    for (int i = threadIdx.x; i < m; i += 256) {
        int pos = base + i;
        if (pos < CAND_CAP) cand[lev * CAND_CAP + pos] = lbuf[i];
    }
}

__global__ __launch_bounds__(1024) void k_final(LevelParams P, const int* cand, const int* count,
                                                const int* wptr, const int* hptr, float* out) {
    // Packed u64 keys: (f32 score bits << 32) | (0xFFFFFFFF - idx).
    // Descending u64 sort == descending score, ties -> ascending index.
    __shared__ unsigned long long sk[CAND_CAP];
    const int lev = blockIdx.x;
    int n = count[lev];
    if (n > CAND_CAP) n = CAND_CAP;
    int size = 1024;
    while (size < n) size <<= 1;  // 1024 / 2048 / 4096

    const float* __restrict__ cls = P.cls[lev];
    const float* __restrict__ pss = P.pss[lev];
    const float* __restrict__ box = P.box[lev];

    for (int i = threadIdx.x; i < size; i += 1024) {
        if (i < n) {
            int idx = cand[lev * CAND_CAP + i];
            float a32 = np_sigmoid_f32(cls[idx]);
            float b32 = np_sigmoid_f32(pss[idx / NUM_CLASSES]);
            float s = __fmul_rn(a32, b32);
            sk[i] = ((unsigned long long)(unsigned)__float_as_int(s) << 32)
                    | (unsigned long long)(0xFFFFFFFFu - (unsigned)idx);
        } else {
            sk[i] = 0ull;
        }
    }
    __syncthreads();

    for (int k = 2; k <= size; k <<= 1) {
        for (int j = k >> 1; j > 0; j >>= 1) {
            for (int t = threadIdx.x; t < (size >> 1); t += 1024) {
                int i = ((t & ~(j - 1)) << 1) | (t & (j - 1));
                int ix = i | j;
                unsigned long long a = sk[i], b = sk[ix];
                bool dirDesc = ((i & k) == 0);
                if ((a > b) != dirDesc) {
                    sk[i] = b; sk[ix] = a;
                }
            }
            __syncthreads();
        }
    }

    const float w = (float)wptr[0], h = (float)hptr[0];
    const float invw = 1.0f / w, invh = 1.0f / h;
    for (int r = threadIdx.x; r < TOPK; r += 1024) {
        unsigned long long v = sk[r];
        float s = __int_as_float((int)(unsigned)(v >> 32));
        int idx = (int)(0xFFFFFFFFu - (unsigned)(v & 0xFFFFFFFFull));
        bool keep = (r < n) && (s > 0.05f);
        int row = lev * TOPK + r;
        float b0 = 0.f, b1 = 0.f, b2 = 0.f, b3 = 0.f;
        if (keep) {
            int a = idx / NUM_CLASSES;
            b0 = fminf(fmaxf(box[a * 4 + 0] * invw, 0.f), 1.f);
            b1 = fminf(fmaxf(box[a * 4 + 1] * invh, 0.f), 1.f);
            b2 = fminf(fmaxf(box[a * 4 + 2] * invw, 0.f), 1.f);
            b3 = fminf(fmaxf(box[a * 4 + 3] * invh, 0.f), 1.f);
        }
        out[row * 4 + 0] = b0;
        out[row * 4 + 1] = b1;
        out[row * 4 + 2] = b2;
        out[row * 4 + 3] = b3;
        out[NUM_LEVELS * TOPK * 4 + row] = keep ? s : 0.0f;
        out[NUM_LEVELS * TOPK * 5 + row] = keep ? (float)(idx % NUM_CLASSES) : -1.0f;
    }
}

extern "C" void kernel_launch(void* const* d_in, const int* in_sizes, int n_in,
                              void* d_out, int out_size, void* d_ws, size_t ws_size,
                              hipStream_t stream) {
    LevelParams P;
    for (int i = 0; i < NUM_LEVELS; ++i) {
        P.cls[i] = (const float*)d_in[3 * i + 0];
        P.box[i] = (const float*)d_in[3 * i + 1];
        P.pss[i] = (const float*)d_in[3 * i + 2];
    }
    const int* wp = (const int*)d_in[15];
    const int* hp = (const int*)d_in[16];

    unsigned char* ws = (unsigned char*)d_ws;
    unsigned* histR = (unsigned*)ws;                     // 32*1280*4 = 163840  [0,163840)
    float* cutL = (float*)(ws + 163840);                 // 20B
    int* count = (int*)(ws + 163860);                    // 20B
    float* gmaxW = (float*)(ws + 163904);                // 13640*4*4 = 218240
    int* cand = (int*)(ws + 382208);                     // 81920

    k_zero<<<40, 256, 0, stream>>>((float4*)histR, count);
    k_hist<<<2560, 256, 0, stream>>>(P, histR, gmaxW);
    k_cutoff<<<NUM_LEVELS, 256, 0, stream>>>(histR, cutL);
    k_compact<<<NGROUPS_TOTAL, 256, 0, stream>>>(P, cutL, gmaxW, count, cand);
    k_final<<<NUM_LEVELS, 1024, 0, stream>>>(P, cand, count, wp, hp, (float*)d_out);
}

// Round 12
// 97.411 us; speedup vs baseline: 3.3571x; 1.0159x over previous
//
#include <hip/hip_runtime.h>
#include <math.h>

#define NUM_LEVELS 5
#define NUM_CLASSES 80
#define TOPK 1000
#define CAND_CAP 4096
#define NBINS 256
#define NREP 32
#define FLOORV 0.5f
#define BIN_W (0.5f / 256.0f)
#define INV_BIN_W (256.0f / 0.5f)

struct LevelParams {
    const float* cls[NUM_LEVELS];
    const float* box[NUM_LEVELS];
    const float* pss[NUM_LEVELS];
};

// Step-rounded f32 sigmoid, numpy scalar semantics (bit-matches golden; R6-R11 pass).
__device__ __forceinline__ float np_sigmoid_f32(float x) {
    float e32 = (float)exp(-(double)x);
    float d = __fadd_rn(1.0f, e32);
    return __fdiv_rn(1.0f, d);
}

__device__ __forceinline__ float max8(float4 a, float4 b) {
    return fmaxf(fmaxf(fmaxf(a.x, a.y), fmaxf(a.z, a.w)),
                 fmaxf(fmaxf(b.x, b.y), fmaxf(b.z, b.w)));
}

// Zero histR (32*1280 u32 = 10240 float4) + count[5].
__global__ __launch_bounds__(256) void k_zero(float4* histR4, int* count) {
    int i = blockIdx.x * 256 + threadIdx.x;
    histR4[i] = make_float4(0.f, 0.f, 0.f, 0.f);  // grid exactly covers 10240
    if (i < NUM_LEVELS) count[i] = 0;
}

// 16 elems/thread (16 divides 80 -> one pss row per thread-iteration).
// Per 8-chunk smax stored to gcmax (coalesced float2/thread) for k_compact.
__global__ __launch_bounds__(256, 8) void k_hist(LevelParams P, unsigned* histR, float2* gcmax) {
    __shared__ unsigned lh[NBINS];
    for (int i = threadIdx.x; i < NBINS; i += 256) lh[i] = 0;
    __syncthreads();

    const int bid = blockIdx.x;
    int lev, lb, nb, G, gs;
    if (bid < 1536)      { lev = 0; lb = bid;        nb = 1536; G = 5120; gs = 0; }
    else if (bid < 1920) { lev = 1; lb = bid - 1536; nb = 384;  G = 1280; gs = 5120; }
    else if (bid < 2016) { lev = 2; lb = bid - 1920; nb = 96;   G = 320;  gs = 6400; }
    else if (bid < 2040) { lev = 3; lb = bid - 2016; nb = 24;   G = 80;   gs = 6720; }
    else                 { lev = 4; lb = bid - 2040; nb = 8;    G = 20;   gs = 6800; }

    const float* __restrict__ cls = P.cls[lev];
    const float* __restrict__ pss = P.pss[lev];
    const int t16 = (int)threadIdx.x * 16;

    int g = lb;
    int e = g * 4096 + t16;
    float4 c0 = *(const float4*)(cls + e);
    float4 c1 = *(const float4*)(cls + e + 4);
    float4 c2 = *(const float4*)(cls + e + 8);
    float4 c3 = *(const float4*)(cls + e + 12);
    float pv = pss[e / NUM_CLASSES];   // 16-elem chunk never crosses a row

    while (g < G) {
        int gn = g + nb;
        int en = ((gn < G) ? gn : g) * 4096 + t16;
        float4 n0 = *(const float4*)(cls + en);
        float4 n1 = *(const float4*)(cls + en + 4);
        float4 n2 = *(const float4*)(cls + en + 8);
        float4 n3 = *(const float4*)(cls + en + 12);
        float npv = pss[en / NUM_CLASSES];

        // ---- compute current (two 8-chunks share A) ----
        float A = 1.0f + __expf(-pv);
        float cm0 = max8(c0, c1);
        float cm1 = max8(c2, c3);
        float E0 = __expf(-cm0);
        float E1 = __expf(-cm1);
        bool p0 = fmaf(E0, A, A) <= 2.0f;   // (1+E)*A <= 2  <=>  smax >= 0.5
        bool p1 = fmaf(E1, A, A) <= 2.0f;
        float sm0 = p0 ? __frcp_rn((1.0f + E0) * A) : 0.0f;
        float sm1 = p1 ? __frcp_rn((1.0f + E1) * A) : 0.0f;
        gcmax[(size_t)(gs + g) * 256 + threadIdx.x] = make_float2(sm0, sm1);

        if (p0 | p1) {
            float cs[16] = {c0.x, c0.y, c0.z, c0.w, c1.x, c1.y, c1.z, c1.w,
                            c2.x, c2.y, c2.z, c2.w, c3.x, c3.y, c3.z, c3.w};
#pragma unroll
            for (int j = 0; j < 16; ++j) {
                float Ej = __expf(-cs[j]);
                if (fmaf(Ej, A, A) <= 2.0f) {
                    float s = __frcp_rn((1.0f + Ej) * A);
                    int b = (int)((s - FLOORV) * INV_BIN_W);
                    if (b < 0) b = 0;
                    if (b > NBINS - 1) b = NBINS - 1;
                    atomicAdd(&lh[b], 1u);
                }
            }
        }

        g = gn; c0 = n0; c1 = n1; c2 = n2; c3 = n3; pv = npv;
    }

    __syncthreads();
    unsigned* h = histR + (size_t)(bid & (NREP - 1)) * (NUM_LEVELS * NBINS) + lev * NBINS;
    for (int i = threadIdx.x; i < NBINS; i += 256) {
        unsigned v = lh[i];
        if (v) atomicAdd(&h[i], v);
    }
}

__global__ __launch_bounds__(256) void k_cutoff(const unsigned* histR, float* cutL) {
    __shared__ unsigned sh[NBINS];
    const int lev = blockIdx.x;
    unsigned s = 0;
#pragma unroll
    for (int r = 0; r < NREP; ++r)
        s += histR[(size_t)r * (NUM_LEVELS * NBINS) + lev * NBINS + threadIdx.x];
    sh[threadIdx.x] = s;
    __syncthreads();
    if (threadIdx.x == 0) {
        long cum = 0;
        int b = NBINS - 1;
        for (; b >= 0; --b) {
            cum += sh[b];
            if (cum >= TOPK) break;
        }
        int sel = (b <= 0) ? 0 : (b - 1);  // one margin bin below crossing
        cutL[lev] = FLOORV + (float)sel * BIN_W;
    }
}

// Thread-per-8-chunk over the smax array; only passing chunks gather cls/pss.
__global__ __launch_bounds__(256) void k_compact(LevelParams P, const float* cutL,
                                                 const float* gcmax, int* count, int* cand) {
    const int bid = blockIdx.x;
    int lev, cstart;
    if (bid < 10240)      { lev = 0; cstart = 0; }
    else if (bid < 12800) { lev = 1; cstart = 2621440; }
    else if (bid < 13440) { lev = 2; cstart = 3276800; }
    else if (bid < 13600) { lev = 3; cstart = 3440640; }
    else                  { lev = 4; cstart = 3481600; }

    const int cid = bid * 256 + (int)threadIdx.x;          // global chunk id
    const float L = cutL[lev];
    const float thr = L - 1e-4f;
    float smax = gcmax[cid];                               // coalesced 4B
    bool pass = smax >= thr - 2e-4f;
    if (__syncthreads_count(pass) == 0) return;

    __shared__ int lcount;
    __shared__ int lbase;
    __shared__ int lbuf[2048];
    if (threadIdx.x == 0) lcount = 0;
    __syncthreads();

    if (pass) {
        const float* __restrict__ cls = P.cls[lev];
        const float* __restrict__ pss = P.pss[lev];
        const int el = (cid - cstart) * 8;                 // level-local element base
        float4 c0 = *(const float4*)(cls + el);
        float4 c1 = *(const float4*)(cls + el + 4);
        float pv = pss[el / NUM_CLASSES];
        float cs[8] = {c0.x, c0.y, c0.z, c0.w, c1.x, c1.y, c1.z, c1.w};
        float A = 1.0f + __expf(-pv);
        float gg = __frcp_rn(thr * A) - 1.0f;              // e^-c <= gg <=> s >= thr
        if (gg > 0.0f) {
            float cthr = -__logf(gg) - 1e-2f;              // conservative raw margin
#pragma unroll
            for (int j = 0; j < 8; ++j) {
                if (cs[j] >= cthr) {
                    int li = atomicAdd(&lcount, 1);
                    if (li < 2048) lbuf[li] = el + j;
                }
            }
        }
    }
    __syncthreads();
    if (threadIdx.x == 0) lbase = atomicAdd(&count[lev], lcount);  // ONE global atomic/block
    __syncthreads();
    const int m = lcount < 2048 ? lcount : 2048;
    const int base = lbase;
    for (int i = threadIdx.x; i < m; i += 256) {
        int pos = base + i;
        if (pos < CAND_CAP) cand[lev * CAND_CAP + pos] = lbuf[i];
    }
}

__global__ __launch_bounds__(1024) void k_final(LevelParams P, const int* cand, const int* count,
                                                const int* wptr, const int* hptr, float* out) {
    // Packed u64 keys: (f32 score bits << 32) | (0xFFFFFFFF - idx).
    // Descending u64 sort == descending score, ties -> ascending index.
    __shared__ unsigned long long sk[CAND_CAP];
    const int lev = blockIdx.x;
    int n = count[lev];
    if (n > CAND_CAP) n = CAND_CAP;
    int size = 1024;
    while (size < n) size <<= 1;  // 1024 / 2048 / 4096

    const float* __restrict__ cls = P.cls[lev];
    const float* __restrict__ pss = P.pss[lev];
    const float* __restrict__ box = P.box[lev];

    for (int i = threadIdx.x; i < size; i += 1024) {
        if (i < n) {
            int idx = cand[lev * CAND_CAP + i];
            float a32 = np_sigmoid_f32(cls[idx]);
            float b32 = np_sigmoid_f32(pss[idx / NUM_CLASSES]);
            float s = __fmul_rn(a32, b32);
            sk[i] = ((unsigned long long)(unsigned)__float_as_int(s) << 32)
                    | (unsigned long long)(0xFFFFFFFFu - (unsigned)idx);
        } else {
            sk[i] = 0ull;
        }
    }
    __syncthreads();

    for (int k = 2; k <= size; k <<= 1) {
        for (int j = k >> 1; j > 0; j >>= 1) {
            for (int t = threadIdx.x; t < (size >> 1); t += 1024) {
                int i = ((t & ~(j - 1)) << 1) | (t & (j - 1));
                int ix = i | j;
                unsigned long long a = sk[i], b = sk[ix];
                bool dirDesc = ((i & k) == 0);
                if ((a > b) != dirDesc) {
                    sk[i] = b; sk[ix] = a;
                }
            }
            __syncthreads();
        }
    }

    const float w = (float)wptr[0], h = (float)hptr[0];
    const float invw = 1.0f / w, invh = 1.0f / h;
    for (int r = threadIdx.x; r < TOPK; r += 1024) {
        unsigned long long v = sk[r];
        float s = __int_as_float((int)(unsigned)(v >> 32));
        int idx = (int)(0xFFFFFFFFu - (unsigned)(v & 0xFFFFFFFFull));
        bool keep = (r < n) && (s > 0.05f);
        int row = lev * TOPK + r;
        float b0 = 0.f, b1 = 0.f, b2 = 0.f, b3 = 0.f;
        if (keep) {
            int a = idx / NUM_CLASSES;
            b0 = fminf(fmaxf(box[a * 4 + 0] * invw, 0.f), 1.f);
            b1 = fminf(fmaxf(box[a * 4 + 1] * invh, 0.f), 1.f);
            b2 = fminf(fmaxf(box[a * 4 + 2] * invw, 0.f), 1.f);
            b3 = fminf(fmaxf(box[a * 4 + 3] * invh, 0.f), 1.f);
        }
        out[row * 4 + 0] = b0;
        out[row * 4 + 1] = b1;
        out[row * 4 + 2] = b2;
        out[row * 4 + 3] = b3;
        out[NUM_LEVELS * TOPK * 4 + row] = keep ? s : 0.0f;
        out[NUM_LEVELS * TOPK * 5 + row] = keep ? (float)(idx % NUM_CLASSES) : -1.0f;
    }
}

extern "C" void kernel_launch(void* const* d_in, const int* in_sizes, int n_in,
                              void* d_out, int out_size, void* d_ws, size_t ws_size,
                              hipStream_t stream) {
    LevelParams P;
    for (int i = 0; i < NUM_LEVELS; ++i) {
        P.cls[i] = (const float*)d_in[3 * i + 0];
        P.box[i] = (const float*)d_in[3 * i + 1];
        P.pss[i] = (const float*)d_in[3 * i + 2];
    }
    const int* wp = (const int*)d_in[15];
    const int* hp = (const int*)d_in[16];

    unsigned char* ws = (unsigned char*)d_ws;
    unsigned* histR = (unsigned*)ws;                     // 163840 B
    float* cutL = (float*)(ws + 163840);                 // 20 B
    int* count = (int*)(ws + 163860);                    // 20 B
    float2* gcmax = (float2*)(ws + 163904);              // 3,491,840 floats = 13,967,360 B
    int* cand = (int*)(ws + 14131264);                   // 81,920 B

    k_zero<<<40, 256, 0, stream>>>((float4*)histR, count);
    k_hist<<<2048, 256, 0, stream>>>(P, histR, gcmax);
    k_cutoff<<<NUM_LEVELS, 256, 0, stream>>>(histR, cutL);
    k_compact<<<13640, 256, 0, stream>>>(P, cutL, (const float*)gcmax, count, cand);
    k_final<<<NUM_LEVELS, 1024, 0, stream>>>(P, cand, count, wp, hp, (float*)d_out);
}